// Round 2
// baseline (699.531 us; speedup 1.0000x reference)
//
#include <hip/hip_runtime.h>
#include <cmath>

// Complete binary tree, level order. Levels 0..20; level d = [2^d - 1, 2^{d+1} - 1).
#define N_NODES_C   ((1 << 21) - 1)   // 2097151
#define N_LEAVES_C  (1 << 20)         // 1048576
#define LEAF_START  (N_LEAVES_C - 1)  // 1048575
#define NFEAT       64

// One thread per node: 16 independent float4 loads (64 floats), no shuffles,
// uniform tanh, coalesced store. W is wave-uniform -> scalar-cached.
__global__ __launch_bounds__(256) void scores_kernel(
        const float* __restrict__ features,
        const float* __restrict__ W,
        const float* __restrict__ b,
        float* __restrict__ scores) {
    const int node = blockIdx.x * 256 + threadIdx.x;
    if (node >= N_NODES_C) return;
    const float4* __restrict__ fp = (const float4*)(features + (size_t)node * NFEAT);
    const float4* __restrict__ wp = (const float4*)W;
    float acc = 0.0f;
#pragma unroll
    for (int k = 0; k < 16; ++k) {
        const float4 f = fp[k];
        const float4 w = wp[k];
        acc += f.x * w.x + f.y * w.y + f.z * w.z + f.w * w.w;
    }
    scores[node] = 1.0f + tanhf(acc + b[0]) * 0.1f;
}

// 1024 blocks x 1024 leaves: reduce levels 19..10 in LDS (ping-pong),
// writing every level's energies to out[].
__global__ __launch_bounds__(256) void stage1_kernel(
        const float* __restrict__ scores,
        const float* __restrict__ leaf_energy,
        float* __restrict__ out) {
    __shared__ float buf[2][1024];
    const int blk = blockIdx.x;          // 1024 blocks
    const int tid = threadIdx.x;
    const int leaf_off = blk * 1024;

    for (int i = tid; i < 1024; i += 256) {
        const int g = LEAF_START + leaf_off + i;
        const float e = leaf_energy[leaf_off + i];
        out[g] = e;
        buf[0][i] = scores[g] * e;
    }
    __syncthreads();

    int p = 0;
    for (int pd = 19; pd >= 10; --pd) {
        const int m = 1 << (pd - 10);                 // 512 .. 1 parents per block
        const int base = (1 << pd) - 1 + blk * m;
        for (int j = tid; j < m; j += 256) {
            const float val = buf[p][2 * j] + buf[p][2 * j + 1];
            out[base + j] = val;
            buf[1 - p][j] = scores[base + j] * val;
        }
        p ^= 1;
        __syncthreads();
    }
}

// One block finishes levels 9..0 from the 1024 level-10 energies out[1023..2047).
__global__ __launch_bounds__(256) void stage2_kernel(
        const float* __restrict__ scores,
        float* __restrict__ out) {
    __shared__ float buf[2][1024];
    const int tid = threadIdx.x;
    for (int i = tid; i < 1024; i += 256)
        buf[0][i] = scores[1023 + i] * out[1023 + i];
    __syncthreads();
    int p = 0;
    for (int pd = 9; pd >= 0; --pd) {
        const int m = 1 << pd;
        const int base = m - 1;
        for (int j = tid; j < m; j += 256) {
            const float val = buf[p][2 * j] + buf[p][2 * j + 1];
            out[base + j] = val;
            buf[1 - p][j] = scores[base + j] * val;
        }
        p ^= 1;
        __syncthreads();
    }
}

extern "C" void kernel_launch(void* const* d_in, const int* in_sizes, int n_in,
                              void* d_out, int out_size, void* d_ws, size_t ws_size,
                              hipStream_t stream) {
    const float* features    = (const float*)d_in[0];  // [N_NODES, 64]
    const float* leaf_energy = (const float*)d_in[1];  // [N_LEAVES]
    const float* W           = (const float*)d_in[2];  // [64]
    const float* b           = (const float*)d_in[3];  // [1]
    float* out    = (float*)d_out;                     // [N_NODES]
    float* scores = (float*)d_ws;                      // N_NODES floats of scratch

    scores_kernel<<<(N_NODES_C + 255) / 256, 256, 0, stream>>>(features, W, b, scores);
    stage1_kernel<<<1024, 256, 0, stream>>>(scores, leaf_energy, out);
    stage2_kernel<<<1, 256, 0, stream>>>(scores, out);
}